// Round 1
// baseline (320.928 us; speedup 1.0000x reference)
//
#include <hip/hip_runtime.h>

// GCN edge predictor, collapsed to scalar-per-node linear algebra:
//   u_i = x_i . w1c ;  v = A u + c1 ;  t = A v + c2 ;  out[g] = sum_g t + c0
//   A = D^-1/2 (Adj + I) D^-1/2
// R5: single-pass binning with atomic slab reservation:
//   scatter_k: block-local counting sort in LDS (as before), per-bucket global
//     segment reserved via int atomicAdd on cursor[] -> fixed-capacity slabs.
//   degree via global int atomicAdd during the scatter load phase.
//   Removes bin_count / scanA / scanB / degree_k (4 kernels, ~26 MB traffic).
//   Int atomics keep counts deterministic; within-bucket edge order becomes
//   tile-arrival dependent, same nondeterminism class as the existing LDS
//   float atomics in the conv kernels.

#define RSHIFT 7
#define RNODES 128           // nodes per bucket
#define NB_MAX 1024          // max buckets (n <= 131072; src fits 17 bits)
#define NBLK 512             // tiles for scatter
#define STHREADS 512
#define STAGE_CAP 8192       // max edges per tile (E <= NBLK*STAGE_CAP)
#define BCAP 6144            // per-bucket slab capacity (mean 4096, +32 sigma)

__global__ void collapse_weights_k(
    const float* __restrict__ W1, const float* __restrict__ b1,
    const float* __restrict__ W2, const float* __restrict__ b2,
    const float* __restrict__ Wf1, const float* __restrict__ bf1,
    const float* __restrict__ Wf2, const float* __restrict__ bf2,
    const float* __restrict__ Wf3, const float* __restrict__ bf3,
    const float* __restrict__ Wo, const float* __restrict__ bo,
    float* __restrict__ w1c, float* __restrict__ sc,
    int* __restrict__ cursor)
{
    __shared__ float wo[10], w3[20], w2[30], w1[50], w2c[60];
    const int t = threadIdx.x;  // 64 threads
    // zero bucket cursors for this run
    for (int b = t; b < NB_MAX; b += 64) cursor[b] = 0;
    if (t < 10) wo[t] = Wo[t];
    __syncthreads();
    if (t < 20) { float s = 0.f; for (int j = 0; j < 10; ++j) s += Wf3[t*10+j]*wo[j]; w3[t] = s; }
    __syncthreads();
    if (t < 30) { float s = 0.f; for (int j = 0; j < 20; ++j) s += Wf2[t*20+j]*w3[j]; w2[t] = s; }
    __syncthreads();
    if (t < 50) { float s = 0.f; for (int j = 0; j < 30; ++j) s += Wf1[t*30+j]*w2[j]; w1[t] = s; }
    __syncthreads();
    if (t < 60) { float s = 0.f; for (int j = 0; j < 50; ++j) s += W2[t*50+j]*w1[j]; w2c[t] = s; }
    __syncthreads();
    { float s = 0.f; for (int j = 0; j < 60; ++j) s += W1[t*60+j]*w2c[j]; w1c[t] = s; }
    if (t == 0) {
        float c1 = 0.f; for (int j = 0; j < 60; ++j) c1 += b1[j]*w2c[j];
        float c2 = 0.f; for (int j = 0; j < 50; ++j) c2 += b2[j]*w1[j];
        float c0 = bo[0];
        for (int j = 0; j < 30; ++j) c0 += bf1[j]*w2[j];
        for (int j = 0; j < 20; ++j) c0 += bf2[j]*w3[j];
        for (int j = 0; j < 10; ++j) c0 += bf3[j]*wo[j];
        sc[0] = c1; sc[1] = c2; sc[2] = c0;
    }
}

// 4 nodes per wave, float4 per 16-lane group: u[i] = x[i,:] . w1c
// Also zeroes deg[] for this run (sub-lane 1 of each node group).
__global__ void node_u_k(const float* __restrict__ x, const float* __restrict__ w1c,
                         float* __restrict__ u, int* __restrict__ deg, int n) {
    int tid = blockIdx.x * blockDim.x + threadIdx.x;
    int wave = tid >> 6;
    int lane = threadIdx.x & 63;
    int node = wave * 4 + (lane >> 4);
    int sub = lane & 15;
    if (node >= n) return;
    if (sub == 1) deg[node] = 0;
    float4 xv = *reinterpret_cast<const float4*>(x + (size_t)node * 64 + sub * 4);
    float4 wv = *reinterpret_cast<const float4*>(w1c + sub * 4);
    float val = xv.x * wv.x + xv.y * wv.y + xv.z * wv.z + xv.w * wv.w;
    val += __shfl_down(val, 8, 16);
    val += __shfl_down(val, 4, 16);
    val += __shfl_down(val, 2, 16);
    val += __shfl_down(val, 1, 16);
    if (sub == 0) u[node] = val;
}

// single-pass bin: block-local counting sort of a tile, global slab reservation
// via cursor[] int atomics, dense flush into bucket slabs. Also accumulates
// per-node in-degree via global int atomics.
__global__ void scatter_k(const int* __restrict__ src, const int* __restrict__ dst,
                          int E, int chunk, int nb,
                          int* __restrict__ cursor, int* __restrict__ deg,
                          unsigned int* __restrict__ binned) {
    __shared__ int hist[NB_MAX];
    __shared__ int tbase[NB_MAX];
    __shared__ int adj[NB_MAX];
    __shared__ int sums[STHREADS];
    __shared__ unsigned int staged[STAGE_CAP];
    __shared__ unsigned short bof[STAGE_CAP];
    const int tid = threadIdx.x;
    hist[tid] = 0; hist[tid + 512] = 0;
    __syncthreads();
    int e0 = blockIdx.x * chunk;
    int e1 = e0 + chunk; if (e1 > E) e1 = E;
    const int QMAX = STAGE_CAP / (STHREADS * 4);   // 4 quads -> 16 edges/thread
    unsigned int pk[QMAX * 4];
    int bk[QMAX * 4];
    int rk[QMAX * 4];
    int nv[QMAX];
    #pragma unroll
    for (int j = 0; j < QMAX; ++j) {
        int i = e0 + tid * 4 + j * (STHREADS * 4);
        int cnt = e1 - i; if (cnt > 4) cnt = 4; if (cnt < 0) cnt = 0;
        nv[j] = cnt;
        if (cnt == 4) {
            int4 s4 = *reinterpret_cast<const int4*>(src + i);
            int4 d4 = *reinterpret_cast<const int4*>(dst + i);
            atomicAdd(&deg[d4.x], 1);
            atomicAdd(&deg[d4.y], 1);
            atomicAdd(&deg[d4.z], 1);
            atomicAdd(&deg[d4.w], 1);
            pk[j*4+0] = (unsigned)s4.x | ((unsigned)(d4.x & (RNODES-1)) << 17);
            pk[j*4+1] = (unsigned)s4.y | ((unsigned)(d4.y & (RNODES-1)) << 17);
            pk[j*4+2] = (unsigned)s4.z | ((unsigned)(d4.z & (RNODES-1)) << 17);
            pk[j*4+3] = (unsigned)s4.w | ((unsigned)(d4.w & (RNODES-1)) << 17);
            bk[j*4+0] = d4.x >> RSHIFT; bk[j*4+1] = d4.y >> RSHIFT;
            bk[j*4+2] = d4.z >> RSHIFT; bk[j*4+3] = d4.w >> RSHIFT;
            rk[j*4+0] = atomicAdd(&hist[bk[j*4+0]], 1);
            rk[j*4+1] = atomicAdd(&hist[bk[j*4+1]], 1);
            rk[j*4+2] = atomicAdd(&hist[bk[j*4+2]], 1);
            rk[j*4+3] = atomicAdd(&hist[bk[j*4+3]], 1);
        } else {
            for (int l = 0; l < cnt; ++l) {
                int s = src[i + l], d = dst[i + l];
                atomicAdd(&deg[d], 1);
                pk[j*4+l] = (unsigned)s | ((unsigned)(d & (RNODES-1)) << 17);
                bk[j*4+l] = d >> RSHIFT;
                rk[j*4+l] = atomicAdd(&hist[bk[j*4+l]], 1);
            }
        }
    }
    __syncthreads();
    // block-exclusive scan of hist[0..1023] (2 slots per thread)
    int h0 = hist[2*tid], h1 = hist[2*tid+1];
    int pair = h0 + h1;
    sums[tid] = pair;
    __syncthreads();
    for (int off = 1; off < STHREADS; off <<= 1) {
        int a = (tid >= off) ? sums[tid - off] : 0;
        __syncthreads();
        sums[tid] += a;
        __syncthreads();
    }
    int excl = sums[tid] - pair;
    tbase[2*tid] = excl;
    tbase[2*tid+1] = excl + h0;
    // reserve this tile's segment in each bucket's slab
    {
        int b0 = 2*tid, b1 = 2*tid + 1;
        if (b0 < nb && h0 > 0) {
            int r = atomicAdd(&cursor[b0], h0);
            adj[b0] = b0 * BCAP + r - excl;
        }
        if (b1 < nb && h1 > 0) {
            int r = atomicAdd(&cursor[b1], h1);
            adj[b1] = b1 * BCAP + r - (excl + h0);
        }
    }
    __syncthreads();
    // write bucket-sorted into LDS
    #pragma unroll
    for (int j = 0; j < QMAX; ++j) {
        for (int l = 0; l < nv[j]; ++l) {
            int b = bk[j*4+l];
            int slot = tbase[b] + rk[j*4+l];
            staged[slot] = pk[j*4+l];
            bof[slot] = (unsigned short)b;
        }
    }
    __syncthreads();
    // dense flush
    int tcount = e1 - e0;
    for (int s = tid; s < tcount; s += STHREADS) {
        int b = bof[s];
        binned[adj[b] + s] = staged[s];
    }
}

// dinv = rsqrt(deg+1); w = dinv * u; also out[g] = c0
__global__ void dinv_w_k(const int* __restrict__ deg, const float* __restrict__ u,
                         float* __restrict__ dinv, float* __restrict__ w,
                         const float* __restrict__ sc, float* __restrict__ out,
                         int n, int G) {
    int g = blockIdx.x * blockDim.x + threadIdx.x;
    if (g < G) out[g] = sc[2];
    if (g < n) {
        float d = rsqrtf((float)(deg[g] + 1));
        dinv[g] = d;
        w[g] = d * u[g];
    }
}

// v = c1 + dinv*(sum of w[src]) + dinv^2*u ; wb = dinv*v
__global__ void conv_mid_k(const unsigned int* __restrict__ binned,
                           const int* __restrict__ cursor,
                           const float* __restrict__ w, const float* __restrict__ dinv,
                           const float* __restrict__ u, const float* __restrict__ sc,
                           float* __restrict__ v, float* __restrict__ wb, int n) {
    __shared__ float acc[RNODES];
    int tid = threadIdx.x, b = blockIdx.x;
    if (tid < RNODES) acc[tid] = 0.f;
    __syncthreads();
    int s0 = b * BCAP;
    int cnt = cursor[b];
    int nvec = cnt >> 2;
    for (int k = tid; k < nvec; k += blockDim.x) {
        uint4 p = *reinterpret_cast<const uint4*>(binned + s0 + 4 * k);
        float wx = w[p.x & 0x1FFFF];
        float wy = w[p.y & 0x1FFFF];
        float wz = w[p.z & 0x1FFFF];
        float ww = w[p.w & 0x1FFFF];
        atomicAdd(&acc[p.x >> 17], wx);
        atomicAdd(&acc[p.y >> 17], wy);
        atomicAdd(&acc[p.z >> 17], wz);
        atomicAdd(&acc[p.w >> 17], ww);
    }
    int i = 4 * nvec + tid;
    if (i < cnt) { unsigned p = binned[s0 + i]; atomicAdd(&acc[p >> 17], w[p & 0x1FFFF]); }
    __syncthreads();
    int g = (b << RSHIFT) + tid;
    if (tid < RNODES && g < n) {
        float di = dinv[g];
        float val = sc[0] + di * acc[tid] + di * di * u[g];
        v[g] = val;
        wb[g] = di * val;
    }
}

// t = c2 + dinv*sum + dinv^2*v, then segmented pool by sorted batch id
__global__ void conv_final_k(const unsigned int* __restrict__ binned,
                             const int* __restrict__ cursor,
                             const float* __restrict__ wb, const float* __restrict__ dinv,
                             const float* __restrict__ v, const float* __restrict__ sc,
                             const int* __restrict__ batch, float* __restrict__ out, int n) {
    __shared__ float acc[RNODES];
    __shared__ float tbuf[RNODES];
    __shared__ int gbuf[RNODES];
    int tid = threadIdx.x, b = blockIdx.x;
    if (tid < RNODES) acc[tid] = 0.f;
    __syncthreads();
    int s0 = b * BCAP;
    int cnt = cursor[b];
    int nvec = cnt >> 2;
    for (int k = tid; k < nvec; k += blockDim.x) {
        uint4 p = *reinterpret_cast<const uint4*>(binned + s0 + 4 * k);
        float wx = wb[p.x & 0x1FFFF];
        float wy = wb[p.y & 0x1FFFF];
        float wz = wb[p.z & 0x1FFFF];
        float ww = wb[p.w & 0x1FFFF];
        atomicAdd(&acc[p.x >> 17], wx);
        atomicAdd(&acc[p.y >> 17], wy);
        atomicAdd(&acc[p.z >> 17], wz);
        atomicAdd(&acc[p.w >> 17], ww);
    }
    int i = 4 * nvec + tid;
    if (i < cnt) { unsigned p = binned[s0 + i]; atomicAdd(&acc[p >> 17], wb[p & 0x1FFFF]); }
    __syncthreads();
    int g = (b << RSHIFT) + tid;
    float tval = 0.f; int gid = -1;
    if (tid < RNODES && g < n) {
        float di = dinv[g];
        tval = sc[1] + di * acc[tid] + di * di * v[g];
        gid = batch[g];
    }
    if (tid < RNODES) { tbuf[tid] = tval; gbuf[tid] = gid; }
    __syncthreads();
    if (tid < RNODES && g < n) {
        bool head = (tid == 0) || (gbuf[tid - 1] != gid);
        if (head) {
            float s = 0.f;
            int i2 = tid;
            while (i2 < RNODES && gbuf[i2] == gid) { s += tbuf[i2]; ++i2; }
            atomicAdd(&out[gid], s);
        }
    }
}

extern "C" void kernel_launch(void* const* d_in, const int* in_sizes, int n_in,
                              void* d_out, int out_size, void* d_ws, size_t ws_size,
                              hipStream_t stream)
{
    const float* x    = (const float*)d_in[0];
    const int*   ei   = (const int*)d_in[1];
    const int*   batch= (const int*)d_in[2];
    const float* W1   = (const float*)d_in[3];
    const float* b1   = (const float*)d_in[4];
    const float* W2   = (const float*)d_in[5];
    const float* b2   = (const float*)d_in[6];
    const float* Wf1  = (const float*)d_in[7];
    const float* bf1  = (const float*)d_in[8];
    const float* Wf2  = (const float*)d_in[9];
    const float* bf2  = (const float*)d_in[10];
    const float* Wf3  = (const float*)d_in[11];
    const float* bf3  = (const float*)d_in[12];
    const float* Wo   = (const float*)d_in[13];
    const float* bo   = (const float*)d_in[14];
    float* out = (float*)d_out;

    const int n = in_sizes[0] / 64;
    const int E = in_sizes[1] / 2;
    const int G = out_size;
    const int* src = ei;
    const int* dst = ei + E;
    const int nb = (n + RNODES - 1) >> RSHIFT;

    // workspace layout (element offsets, all blocks 16B-aligned)
    float* ws_f = (float*)d_ws;
    int*   ws_i = (int*)d_ws;
    float* w1c    = ws_f;                    // 64
    float* sc     = ws_f + 64;               // 3 (+pad to 128)
    int*   cursor = ws_i + 128;              // NB_MAX
    int*   deg    = ws_i + 128 + NB_MAX;     // n
    size_t off_u  = 128 + (size_t)NB_MAX + n;
    off_u = (off_u + 3) & ~(size_t)3;
    float* u      = ws_f + off_u;            // n
    float* dinv   = u + n;                   // n
    float* w      = dinv + n;                // n
    float* v      = w + n;                   // n
    float* wb     = v + n;                   // n
    size_t off_b  = off_u + 5*(size_t)n;
    off_b = (off_b + 3) & ~(size_t)3;
    unsigned int* binned = (unsigned int*)(ws_f + off_b);   // nb * BCAP

    int chunk = (E + NBLK - 1) / NBLK;
    chunk = (chunk + 3) & ~3;

    hipLaunchKernelGGL(collapse_weights_k, dim3(1), dim3(64), 0, stream,
                       W1, b1, W2, b2, Wf1, bf1, Wf2, bf2, Wf3, bf3, Wo, bo,
                       w1c, sc, cursor);
    hipLaunchKernelGGL(node_u_k, dim3((n / 4 * 64 + 255) / 256 + 1), dim3(256), 0, stream,
                       x, w1c, u, deg, n);
    hipLaunchKernelGGL(scatter_k, dim3(NBLK), dim3(STHREADS), 0, stream,
                       src, dst, E, chunk, nb, cursor, deg, binned);
    hipLaunchKernelGGL(dinv_w_k, dim3((n + 255) / 256), dim3(256), 0, stream,
                       deg, u, dinv, w, sc, out, n, G);
    hipLaunchKernelGGL(conv_mid_k, dim3(nb), dim3(512), 0, stream,
                       binned, cursor, w, dinv, u, sc, v, wb, n);
    hipLaunchKernelGGL(conv_final_k, dim3(nb), dim3(512), 0, stream,
                       binned, cursor, wb, dinv, v, sc, batch, out, n);
}

// Round 2
// 210.507 us; speedup vs baseline: 1.5245x; 1.5245x over previous
//
#include <hip/hip_runtime.h>

// GCN edge predictor, collapsed to scalar-per-node linear algebra:
//   u_i = x_i . w1c ;  v = A u + c1 ;  t = A v + c2 ;  out[g] = sum_g t + c0
//   A = D^-1/2 (Adj + I) D^-1/2
// R6: single-pass slab binning (R5) WITHOUT per-edge global atomics (the R5
//   regression: 3.2M global deg atomicAdds -> 122MB write-through + serialization).
//   Degree is recomputed bucket-locally in LDS from the binned array
//   (restored R4 degree_k), fused with dinv/w computation. out-init moves to
//   node_u_k. Pipeline: collapse, node_u, scatter, degree_dinv, conv_mid,
//   conv_final (6 kernels, no bin_count/scanA/scanB).

#define RSHIFT 7
#define RNODES 128           // nodes per bucket
#define NB_MAX 1024          // max buckets (n <= 131072; src fits 17 bits)
#define NBLK 512             // tiles for scatter
#define STHREADS 512
#define STAGE_CAP 8192       // max edges per tile (E <= NBLK*STAGE_CAP)
#define BCAP 6144            // per-bucket slab capacity (mean 4092, +32 sigma)

__global__ void collapse_weights_k(
    const float* __restrict__ W1, const float* __restrict__ b1,
    const float* __restrict__ W2, const float* __restrict__ b2,
    const float* __restrict__ Wf1, const float* __restrict__ bf1,
    const float* __restrict__ Wf2, const float* __restrict__ bf2,
    const float* __restrict__ Wf3, const float* __restrict__ bf3,
    const float* __restrict__ Wo, const float* __restrict__ bo,
    float* __restrict__ w1c, float* __restrict__ sc,
    int* __restrict__ cursor)
{
    __shared__ float wo[10], w3[20], w2[30], w1[50], w2c[60];
    const int t = threadIdx.x;  // 64 threads
    // zero bucket cursors for this run
    for (int b = t; b < NB_MAX; b += 64) cursor[b] = 0;
    if (t < 10) wo[t] = Wo[t];
    __syncthreads();
    if (t < 20) { float s = 0.f; for (int j = 0; j < 10; ++j) s += Wf3[t*10+j]*wo[j]; w3[t] = s; }
    __syncthreads();
    if (t < 30) { float s = 0.f; for (int j = 0; j < 20; ++j) s += Wf2[t*20+j]*w3[j]; w2[t] = s; }
    __syncthreads();
    if (t < 50) { float s = 0.f; for (int j = 0; j < 30; ++j) s += Wf1[t*30+j]*w2[j]; w1[t] = s; }
    __syncthreads();
    if (t < 60) { float s = 0.f; for (int j = 0; j < 50; ++j) s += W2[t*50+j]*w1[j]; w2c[t] = s; }
    __syncthreads();
    { float s = 0.f; for (int j = 0; j < 60; ++j) s += W1[t*60+j]*w2c[j]; w1c[t] = s; }
    if (t == 0) {
        float c1 = 0.f; for (int j = 0; j < 60; ++j) c1 += b1[j]*w2c[j];
        float c2 = 0.f; for (int j = 0; j < 50; ++j) c2 += b2[j]*w1[j];
        float c0 = bo[0];
        for (int j = 0; j < 30; ++j) c0 += bf1[j]*w2[j];
        for (int j = 0; j < 20; ++j) c0 += bf2[j]*w3[j];
        for (int j = 0; j < 10; ++j) c0 += bf3[j]*wo[j];
        sc[0] = c1; sc[1] = c2; sc[2] = c0;
    }
}

// 4 nodes per wave, float4 per 16-lane group: u[i] = x[i,:] . w1c
// Also initializes out[g] = c0 (first G flat threads).
__global__ void node_u_k(const float* __restrict__ x, const float* __restrict__ w1c,
                         float* __restrict__ u,
                         const float* __restrict__ sc, float* __restrict__ out,
                         int n, int G) {
    int tid = blockIdx.x * blockDim.x + threadIdx.x;
    if (tid < G) out[tid] = sc[2];
    int wave = tid >> 6;
    int lane = threadIdx.x & 63;
    int node = wave * 4 + (lane >> 4);
    int sub = lane & 15;
    if (node >= n) return;
    float4 xv = *reinterpret_cast<const float4*>(x + (size_t)node * 64 + sub * 4);
    float4 wv = *reinterpret_cast<const float4*>(w1c + sub * 4);
    float val = xv.x * wv.x + xv.y * wv.y + xv.z * wv.z + xv.w * wv.w;
    val += __shfl_down(val, 8, 16);
    val += __shfl_down(val, 4, 16);
    val += __shfl_down(val, 2, 16);
    val += __shfl_down(val, 1, 16);
    if (sub == 0) u[node] = val;
}

// single-pass bin: block-local counting sort of a tile, global slab reservation
// via cursor[] int atomics (one per (bucket,tile) pair), dense flush into
// bucket slabs. No per-edge global atomics.
__global__ void scatter_k(const int* __restrict__ src, const int* __restrict__ dst,
                          int E, int chunk, int nb,
                          int* __restrict__ cursor,
                          unsigned int* __restrict__ binned) {
    __shared__ int hist[NB_MAX];
    __shared__ int tbase[NB_MAX];
    __shared__ int adj[NB_MAX];
    __shared__ int sums[STHREADS];
    __shared__ unsigned int staged[STAGE_CAP];
    __shared__ unsigned short bof[STAGE_CAP];
    const int tid = threadIdx.x;
    hist[tid] = 0; hist[tid + 512] = 0;
    __syncthreads();
    int e0 = blockIdx.x * chunk;
    int e1 = e0 + chunk; if (e1 > E) e1 = E;
    const int QMAX = STAGE_CAP / (STHREADS * 4);   // 4 quads -> 16 edges/thread
    unsigned int pk[QMAX * 4];
    int bk[QMAX * 4];
    int rk[QMAX * 4];
    int nv[QMAX];
    #pragma unroll
    for (int j = 0; j < QMAX; ++j) {
        int i = e0 + tid * 4 + j * (STHREADS * 4);
        int cnt = e1 - i; if (cnt > 4) cnt = 4; if (cnt < 0) cnt = 0;
        nv[j] = cnt;
        if (cnt == 4) {
            int4 s4 = *reinterpret_cast<const int4*>(src + i);
            int4 d4 = *reinterpret_cast<const int4*>(dst + i);
            pk[j*4+0] = (unsigned)s4.x | ((unsigned)(d4.x & (RNODES-1)) << 17);
            pk[j*4+1] = (unsigned)s4.y | ((unsigned)(d4.y & (RNODES-1)) << 17);
            pk[j*4+2] = (unsigned)s4.z | ((unsigned)(d4.z & (RNODES-1)) << 17);
            pk[j*4+3] = (unsigned)s4.w | ((unsigned)(d4.w & (RNODES-1)) << 17);
            bk[j*4+0] = d4.x >> RSHIFT; bk[j*4+1] = d4.y >> RSHIFT;
            bk[j*4+2] = d4.z >> RSHIFT; bk[j*4+3] = d4.w >> RSHIFT;
            rk[j*4+0] = atomicAdd(&hist[bk[j*4+0]], 1);
            rk[j*4+1] = atomicAdd(&hist[bk[j*4+1]], 1);
            rk[j*4+2] = atomicAdd(&hist[bk[j*4+2]], 1);
            rk[j*4+3] = atomicAdd(&hist[bk[j*4+3]], 1);
        } else {
            for (int l = 0; l < cnt; ++l) {
                int s = src[i + l], d = dst[i + l];
                pk[j*4+l] = (unsigned)s | ((unsigned)(d & (RNODES-1)) << 17);
                bk[j*4+l] = d >> RSHIFT;
                rk[j*4+l] = atomicAdd(&hist[bk[j*4+l]], 1);
            }
        }
    }
    __syncthreads();
    // block-exclusive scan of hist[0..1023] (2 slots per thread)
    int h0 = hist[2*tid], h1 = hist[2*tid+1];
    int pair = h0 + h1;
    sums[tid] = pair;
    __syncthreads();
    for (int off = 1; off < STHREADS; off <<= 1) {
        int a = (tid >= off) ? sums[tid - off] : 0;
        __syncthreads();
        sums[tid] += a;
        __syncthreads();
    }
    int excl = sums[tid] - pair;
    tbase[2*tid] = excl;
    tbase[2*tid+1] = excl + h0;
    // reserve this tile's segment in each bucket's slab
    {
        int b0 = 2*tid, b1 = 2*tid + 1;
        if (b0 < nb && h0 > 0) {
            int r = atomicAdd(&cursor[b0], h0);
            adj[b0] = b0 * BCAP + r - excl;
        }
        if (b1 < nb && h1 > 0) {
            int r = atomicAdd(&cursor[b1], h1);
            adj[b1] = b1 * BCAP + r - (excl + h0);
        }
    }
    __syncthreads();
    // write bucket-sorted into LDS
    #pragma unroll
    for (int j = 0; j < QMAX; ++j) {
        for (int l = 0; l < nv[j]; ++l) {
            int b = bk[j*4+l];
            int slot = tbase[b] + rk[j*4+l];
            staged[slot] = pk[j*4+l];
            bof[slot] = (unsigned short)b;
        }
    }
    __syncthreads();
    // dense flush
    int tcount = e1 - e0;
    for (int s = tid; s < tcount; s += STHREADS) {
        int b = bof[s];
        binned[adj[b] + s] = staged[s];
    }
}

// per-bucket in-degree histogram in LDS -> dinv = rsqrt(deg+1); w = dinv * u
__global__ void degree_dinv_k(const unsigned int* __restrict__ binned,
                              const int* __restrict__ cursor,
                              const float* __restrict__ u,
                              float* __restrict__ dinv, float* __restrict__ w, int n) {
    __shared__ int cnt[RNODES];
    int tid = threadIdx.x, b = blockIdx.x;
    if (tid < RNODES) cnt[tid] = 0;
    __syncthreads();
    int s0 = b * BCAP;
    int c = cursor[b];
    int nvec = c >> 2;
    for (int k = tid; k < nvec; k += blockDim.x) {
        uint4 p = *reinterpret_cast<const uint4*>(binned + s0 + 4 * k);
        atomicAdd(&cnt[p.x >> 17], 1);
        atomicAdd(&cnt[p.y >> 17], 1);
        atomicAdd(&cnt[p.z >> 17], 1);
        atomicAdd(&cnt[p.w >> 17], 1);
    }
    int i = 4 * nvec + tid;
    if (i < c) atomicAdd(&cnt[binned[s0 + i] >> 17], 1);
    __syncthreads();
    int g = (b << RSHIFT) + tid;
    if (tid < RNODES && g < n) {
        float d = rsqrtf((float)(cnt[tid] + 1));
        dinv[g] = d;
        w[g] = d * u[g];
    }
}

// v = c1 + dinv*(sum of w[src]) + dinv^2*u ; wb = dinv*v
__global__ void conv_mid_k(const unsigned int* __restrict__ binned,
                           const int* __restrict__ cursor,
                           const float* __restrict__ w, const float* __restrict__ dinv,
                           const float* __restrict__ u, const float* __restrict__ sc,
                           float* __restrict__ v, float* __restrict__ wb, int n) {
    __shared__ float acc[RNODES];
    int tid = threadIdx.x, b = blockIdx.x;
    if (tid < RNODES) acc[tid] = 0.f;
    __syncthreads();
    int s0 = b * BCAP;
    int cnt = cursor[b];
    int nvec = cnt >> 2;
    for (int k = tid; k < nvec; k += blockDim.x) {
        uint4 p = *reinterpret_cast<const uint4*>(binned + s0 + 4 * k);
        float wx = w[p.x & 0x1FFFF];
        float wy = w[p.y & 0x1FFFF];
        float wz = w[p.z & 0x1FFFF];
        float ww = w[p.w & 0x1FFFF];
        atomicAdd(&acc[p.x >> 17], wx);
        atomicAdd(&acc[p.y >> 17], wy);
        atomicAdd(&acc[p.z >> 17], wz);
        atomicAdd(&acc[p.w >> 17], ww);
    }
    int i = 4 * nvec + tid;
    if (i < cnt) { unsigned p = binned[s0 + i]; atomicAdd(&acc[p >> 17], w[p & 0x1FFFF]); }
    __syncthreads();
    int g = (b << RSHIFT) + tid;
    if (tid < RNODES && g < n) {
        float di = dinv[g];
        float val = sc[0] + di * acc[tid] + di * di * u[g];
        v[g] = val;
        wb[g] = di * val;
    }
}

// t = c2 + dinv*sum + dinv^2*v, then segmented pool by sorted batch id
__global__ void conv_final_k(const unsigned int* __restrict__ binned,
                             const int* __restrict__ cursor,
                             const float* __restrict__ wb, const float* __restrict__ dinv,
                             const float* __restrict__ v, const float* __restrict__ sc,
                             const int* __restrict__ batch, float* __restrict__ out, int n) {
    __shared__ float acc[RNODES];
    __shared__ float tbuf[RNODES];
    __shared__ int gbuf[RNODES];
    int tid = threadIdx.x, b = blockIdx.x;
    if (tid < RNODES) acc[tid] = 0.f;
    __syncthreads();
    int s0 = b * BCAP;
    int cnt = cursor[b];
    int nvec = cnt >> 2;
    for (int k = tid; k < nvec; k += blockDim.x) {
        uint4 p = *reinterpret_cast<const uint4*>(binned + s0 + 4 * k);
        float wx = wb[p.x & 0x1FFFF];
        float wy = wb[p.y & 0x1FFFF];
        float wz = wb[p.z & 0x1FFFF];
        float ww = wb[p.w & 0x1FFFF];
        atomicAdd(&acc[p.x >> 17], wx);
        atomicAdd(&acc[p.y >> 17], wy);
        atomicAdd(&acc[p.z >> 17], wz);
        atomicAdd(&acc[p.w >> 17], ww);
    }
    int i = 4 * nvec + tid;
    if (i < cnt) { unsigned p = binned[s0 + i]; atomicAdd(&acc[p >> 17], wb[p & 0x1FFFF]); }
    __syncthreads();
    int g = (b << RSHIFT) + tid;
    float tval = 0.f; int gid = -1;
    if (tid < RNODES && g < n) {
        float di = dinv[g];
        tval = sc[1] + di * acc[tid] + di * di * v[g];
        gid = batch[g];
    }
    if (tid < RNODES) { tbuf[tid] = tval; gbuf[tid] = gid; }
    __syncthreads();
    if (tid < RNODES && g < n) {
        bool head = (tid == 0) || (gbuf[tid - 1] != gid);
        if (head) {
            float s = 0.f;
            int i2 = tid;
            while (i2 < RNODES && gbuf[i2] == gid) { s += tbuf[i2]; ++i2; }
            atomicAdd(&out[gid], s);
        }
    }
}

extern "C" void kernel_launch(void* const* d_in, const int* in_sizes, int n_in,
                              void* d_out, int out_size, void* d_ws, size_t ws_size,
                              hipStream_t stream)
{
    const float* x    = (const float*)d_in[0];
    const int*   ei   = (const int*)d_in[1];
    const int*   batch= (const int*)d_in[2];
    const float* W1   = (const float*)d_in[3];
    const float* b1   = (const float*)d_in[4];
    const float* W2   = (const float*)d_in[5];
    const float* b2   = (const float*)d_in[6];
    const float* Wf1  = (const float*)d_in[7];
    const float* bf1  = (const float*)d_in[8];
    const float* Wf2  = (const float*)d_in[9];
    const float* bf2  = (const float*)d_in[10];
    const float* Wf3  = (const float*)d_in[11];
    const float* bf3  = (const float*)d_in[12];
    const float* Wo   = (const float*)d_in[13];
    const float* bo   = (const float*)d_in[14];
    float* out = (float*)d_out;

    const int n = in_sizes[0] / 64;
    const int E = in_sizes[1] / 2;
    const int G = out_size;
    const int* src = ei;
    const int* dst = ei + E;
    const int nb = (n + RNODES - 1) >> RSHIFT;

    // workspace layout (element offsets, all blocks 16B-aligned)
    float* ws_f = (float*)d_ws;
    int*   ws_i = (int*)d_ws;
    float* w1c    = ws_f;                    // 64
    float* sc     = ws_f + 64;               // 3 (+pad to 128)
    int*   cursor = ws_i + 128;              // NB_MAX
    size_t off_u  = 128 + (size_t)NB_MAX;
    float* u      = ws_f + off_u;            // n
    float* dinv   = u + n;                   // n
    float* w      = dinv + n;                // n
    float* v      = w + n;                   // n
    float* wb     = v + n;                   // n
    size_t off_b  = off_u + 5*(size_t)n;
    off_b = (off_b + 3) & ~(size_t)3;
    unsigned int* binned = (unsigned int*)(ws_f + off_b);   // nb * BCAP

    int chunk = (E + NBLK - 1) / NBLK;
    chunk = (chunk + 3) & ~3;

    hipLaunchKernelGGL(collapse_weights_k, dim3(1), dim3(64), 0, stream,
                       W1, b1, W2, b2, Wf1, bf1, Wf2, bf2, Wf3, bf3, Wo, bo,
                       w1c, sc, cursor);
    hipLaunchKernelGGL(node_u_k, dim3((n / 4 * 64 + 255) / 256 + 1), dim3(256), 0, stream,
                       x, w1c, u, sc, out, n, G);
    hipLaunchKernelGGL(scatter_k, dim3(NBLK), dim3(STHREADS), 0, stream,
                       src, dst, E, chunk, nb, cursor, binned);
    hipLaunchKernelGGL(degree_dinv_k, dim3(nb), dim3(512), 0, stream,
                       binned, cursor, u, dinv, w, n);
    hipLaunchKernelGGL(conv_mid_k, dim3(nb), dim3(512), 0, stream,
                       binned, cursor, w, dinv, u, sc, v, wb, n);
    hipLaunchKernelGGL(conv_final_k, dim3(nb), dim3(512), 0, stream,
                       binned, cursor, wb, dinv, v, sc, batch, out, n);
}

// Round 4
// 203.127 us; speedup vs baseline: 1.5799x; 1.0363x over previous
//
#include <hip/hip_runtime.h>

// GCN edge predictor, collapsed to scalar-per-node linear algebra:
//   u_i = x_i . w1c ;  v = A u + c1 ;  t = A v + c2 ;  out[g] = sum_g t + c0
//   A = D^-1/2 (Adj + I) D^-1/2
// R8: R6 structure (kernel boundaries = free cross-XCD coherence; R7's
//   cooperative fusion broke on per-XCD L2 non-coherence), with:
//   - scatter scratch demotion FIXED: partial-quad paths statically unrolled
//     with guards so pk/bk/rk stay in VGPRs (R5/R6 showed VGPR_Count=32 ->
//     52 words/thread spilled to scratch, ~200MB hidden traffic).
//   - node_u fused into scatter (independent outputs; x-read overlaps
//     scatter latency; one fewer launch).
//   - cursor zero + out init moved into collapse_weights_k (one fewer launch).
//   Pipeline: collapse, scatter+u, degree_dinv, conv_mid, conv_final (5).

#define RSHIFT 7
#define RNODES 128           // nodes per bucket
#define NB_MAX 1024          // max buckets (n <= 131072; src fits 17 bits)
#define GRID 512             // scatter tiles
#define THREADS 512
#define STAGE_CAP 8192       // max edges per tile
#define BCAP 6144            // per-bucket slab capacity (mean 4092, +32 sigma)

__global__ void collapse_weights_k(
    const float* __restrict__ W1, const float* __restrict__ b1,
    const float* __restrict__ W2, const float* __restrict__ b2,
    const float* __restrict__ Wf1, const float* __restrict__ bf1,
    const float* __restrict__ Wf2, const float* __restrict__ bf2,
    const float* __restrict__ Wf3, const float* __restrict__ bf3,
    const float* __restrict__ Wo, const float* __restrict__ bo,
    float* __restrict__ w1c, float* __restrict__ sc,
    int* __restrict__ cursor, float* __restrict__ out, int G)
{
    __shared__ float wo[10], w3[20], w2[30], w1[50], w2c[60];
    __shared__ float c0s;
    const int t = threadIdx.x;  // 64 threads
    for (int b = t; b < NB_MAX; b += 64) cursor[b] = 0;
    if (t < 10) wo[t] = Wo[t];
    __syncthreads();
    if (t < 20) { float s = 0.f; for (int j = 0; j < 10; ++j) s += Wf3[t*10+j]*wo[j]; w3[t] = s; }
    __syncthreads();
    if (t < 30) { float s = 0.f; for (int j = 0; j < 20; ++j) s += Wf2[t*20+j]*w3[j]; w2[t] = s; }
    __syncthreads();
    if (t < 50) { float s = 0.f; for (int j = 0; j < 30; ++j) s += Wf1[t*30+j]*w2[j]; w1[t] = s; }
    __syncthreads();
    if (t < 60) { float s = 0.f; for (int j = 0; j < 50; ++j) s += W2[t*50+j]*w1[j]; w2c[t] = s; }
    __syncthreads();
    { float s = 0.f; for (int j = 0; j < 60; ++j) s += W1[t*60+j]*w2c[j]; w1c[t] = s; }
    if (t == 0) {
        float c1 = 0.f; for (int j = 0; j < 60; ++j) c1 += b1[j]*w2c[j];
        float c2 = 0.f; for (int j = 0; j < 50; ++j) c2 += b2[j]*w1[j];
        float c0 = bo[0];
        for (int j = 0; j < 30; ++j) c0 += bf1[j]*w2[j];
        for (int j = 0; j < 20; ++j) c0 += bf2[j]*w3[j];
        for (int j = 0; j < 10; ++j) c0 += bf3[j]*wo[j];
        sc[0] = c1; sc[1] = c2; sc[2] = c0;
        c0s = c0;
    }
    __syncthreads();
    for (int g = t; g < G; g += 64) out[g] = c0s;
}

// Fused: (A) u for this block's node slice; (B) scatter tile bx into slabs.
// Independent outputs -> no intra-kernel ordering needed between A and B.
__global__ __launch_bounds__(THREADS, 4)
void scatter_u_k(const float* __restrict__ x, const float* __restrict__ w1c,
                 float* __restrict__ u,
                 const int* __restrict__ src, const int* __restrict__ dst,
                 int E, int n, int npb, int chunk, int nb,
                 int* __restrict__ cursor, unsigned int* __restrict__ binned) {
    __shared__ int hist[NB_MAX];
    __shared__ int tbase[NB_MAX];
    __shared__ int adj[NB_MAX];
    __shared__ int sums[THREADS];
    __shared__ unsigned int staged[STAGE_CAP];
    __shared__ unsigned short bof[STAGE_CAP];
    const int tid = threadIdx.x;
    const int bx = blockIdx.x;

    // ---- (A) u for nodes [bx*npb, bx*npb+npb) ----
    {
        const int grp = tid >> 4, sub = tid & 15;
        float4 wv = *reinterpret_cast<const float4*>(w1c + sub * 4);
        int base = bx * npb;
        for (int p = 0; p * 32 < npb; ++p) {
            int nl = p * 32 + grp;
            int g = base + nl;
            bool ok = (nl < npb) && (g < n);
            float val = 0.f;
            if (ok) {
                float4 xv = *reinterpret_cast<const float4*>(
                    x + (size_t)g * 64 + sub * 4);
                val = xv.x*wv.x + xv.y*wv.y + xv.z*wv.z + xv.w*wv.w;
            }
            val += __shfl_down(val, 8, 16);
            val += __shfl_down(val, 4, 16);
            val += __shfl_down(val, 2, 16);
            val += __shfl_down(val, 1, 16);
            if (ok && sub == 0) u[g] = val;
        }
    }

    // ---- (B) scatter tile bx ----
    hist[tid] = 0; hist[tid + THREADS] = 0;
    __syncthreads();
    int e0 = bx * chunk;
    int e1 = e0 + chunk; if (e1 > E) e1 = E;
    const int QMAX = STAGE_CAP / (THREADS * 4);   // 4 -> 16 edges/thread
    unsigned int pk[QMAX * 4];
    int bk[QMAX * 4];
    int rk[QMAX * 4];
    int nv[QMAX];
    #pragma unroll
    for (int j = 0; j < QMAX; ++j) {
        int i = e0 + tid * 4 + j * (THREADS * 4);
        int cnt = e1 - i; if (cnt > 4) cnt = 4; if (cnt < 0) cnt = 0;
        nv[j] = cnt;
        if (cnt == 4) {
            int4 s4 = *reinterpret_cast<const int4*>(src + i);
            int4 d4 = *reinterpret_cast<const int4*>(dst + i);
            pk[j*4+0] = (unsigned)s4.x | ((unsigned)(d4.x & (RNODES-1)) << 17);
            pk[j*4+1] = (unsigned)s4.y | ((unsigned)(d4.y & (RNODES-1)) << 17);
            pk[j*4+2] = (unsigned)s4.z | ((unsigned)(d4.z & (RNODES-1)) << 17);
            pk[j*4+3] = (unsigned)s4.w | ((unsigned)(d4.w & (RNODES-1)) << 17);
            bk[j*4+0] = d4.x >> RSHIFT; bk[j*4+1] = d4.y >> RSHIFT;
            bk[j*4+2] = d4.z >> RSHIFT; bk[j*4+3] = d4.w >> RSHIFT;
            rk[j*4+0] = atomicAdd(&hist[bk[j*4+0]], 1);
            rk[j*4+1] = atomicAdd(&hist[bk[j*4+1]], 1);
            rk[j*4+2] = atomicAdd(&hist[bk[j*4+2]], 1);
            rk[j*4+3] = atomicAdd(&hist[bk[j*4+3]], 1);
        } else {
            // static unroll with guards: keeps pk/bk/rk in VGPRs (rule #20)
            #pragma unroll
            for (int l = 0; l < 4; ++l) {
                if (l < cnt) {
                    int s = src[i + l], d = dst[i + l];
                    pk[j*4+l] = (unsigned)s | ((unsigned)(d & (RNODES-1)) << 17);
                    bk[j*4+l] = d >> RSHIFT;
                    rk[j*4+l] = atomicAdd(&hist[bk[j*4+l]], 1);
                }
            }
        }
    }
    __syncthreads();
    // block-exclusive scan of hist[0..1023] (2 slots per thread)
    int h0 = hist[2*tid], h1 = hist[2*tid+1];
    int pair = h0 + h1;
    sums[tid] = pair;
    __syncthreads();
    for (int off = 1; off < THREADS; off <<= 1) {
        int a = (tid >= off) ? sums[tid - off] : 0;
        __syncthreads();
        sums[tid] += a;
        __syncthreads();
    }
    int excl = sums[tid] - pair;
    tbase[2*tid] = excl;
    tbase[2*tid+1] = excl + h0;
    // reserve this tile's segment in each bucket's slab
    {
        int b0 = 2*tid, b1 = 2*tid + 1;
        if (b0 < nb && h0 > 0) {
            int r = atomicAdd(&cursor[b0], h0);
            adj[b0] = b0 * BCAP + r - excl;
        }
        if (b1 < nb && h1 > 0) {
            int r = atomicAdd(&cursor[b1], h1);
            adj[b1] = b1 * BCAP + r - (excl + h0);
        }
    }
    __syncthreads();
    // write bucket-sorted into LDS (static unroll, guarded)
    #pragma unroll
    for (int j = 0; j < QMAX; ++j) {
        #pragma unroll
        for (int l = 0; l < 4; ++l) {
            if (l < nv[j]) {
                int b = bk[j*4+l];
                int slot = tbase[b] + rk[j*4+l];
                staged[slot] = pk[j*4+l];
                bof[slot] = (unsigned short)b;
            }
        }
    }
    __syncthreads();
    // dense flush
    int tcount = e1 - e0;
    for (int s = tid; s < tcount; s += THREADS) {
        int b = bof[s];
        binned[adj[b] + s] = staged[s];
    }
}

// per-bucket in-degree histogram in LDS -> dinv = rsqrt(deg+1); w = dinv * u
__global__ void degree_dinv_k(const unsigned int* __restrict__ binned,
                              const int* __restrict__ cursor,
                              const float* __restrict__ u,
                              float* __restrict__ dinv, float* __restrict__ w, int n) {
    __shared__ int cnt[RNODES];
    int tid = threadIdx.x, b = blockIdx.x;
    if (tid < RNODES) cnt[tid] = 0;
    __syncthreads();
    int s0 = b * BCAP;
    int c = cursor[b];
    if (c > BCAP) c = BCAP;
    int nvec = c >> 2;
    for (int k = tid; k < nvec; k += blockDim.x) {
        uint4 p = *reinterpret_cast<const uint4*>(binned + s0 + 4 * k);
        atomicAdd(&cnt[p.x >> 17], 1);
        atomicAdd(&cnt[p.y >> 17], 1);
        atomicAdd(&cnt[p.z >> 17], 1);
        atomicAdd(&cnt[p.w >> 17], 1);
    }
    int i = 4 * nvec + tid;
    if (i < c) atomicAdd(&cnt[binned[s0 + i] >> 17], 1);
    __syncthreads();
    int g = (b << RSHIFT) + tid;
    if (tid < RNODES && g < n) {
        float d = rsqrtf((float)(cnt[tid] + 1));
        dinv[g] = d;
        w[g] = d * u[g];
    }
}

// v = c1 + dinv*(sum of w[src]) + dinv^2*u ; wb = dinv*v
__global__ void conv_mid_k(const unsigned int* __restrict__ binned,
                           const int* __restrict__ cursor,
                           const float* __restrict__ w, const float* __restrict__ dinv,
                           const float* __restrict__ u, const float* __restrict__ sc,
                           float* __restrict__ v, float* __restrict__ wb, int n) {
    __shared__ float acc[RNODES];
    int tid = threadIdx.x, b = blockIdx.x;
    if (tid < RNODES) acc[tid] = 0.f;
    __syncthreads();
    int s0 = b * BCAP;
    int cnt = cursor[b];
    if (cnt > BCAP) cnt = BCAP;
    int nvec = cnt >> 2;
    for (int k = tid; k < nvec; k += blockDim.x) {
        uint4 p = *reinterpret_cast<const uint4*>(binned + s0 + 4 * k);
        float wx = w[p.x & 0x1FFFF];
        float wy = w[p.y & 0x1FFFF];
        float wz = w[p.z & 0x1FFFF];
        float ww = w[p.w & 0x1FFFF];
        atomicAdd(&acc[p.x >> 17], wx);
        atomicAdd(&acc[p.y >> 17], wy);
        atomicAdd(&acc[p.z >> 17], wz);
        atomicAdd(&acc[p.w >> 17], ww);
    }
    int i = 4 * nvec + tid;
    if (i < cnt) { unsigned p = binned[s0 + i]; atomicAdd(&acc[p >> 17], w[p & 0x1FFFF]); }
    __syncthreads();
    int g = (b << RSHIFT) + tid;
    if (tid < RNODES && g < n) {
        float di = dinv[g];
        float val = sc[0] + di * acc[tid] + di * di * u[g];
        v[g] = val;
        wb[g] = di * val;
    }
}

// t = c2 + dinv*sum + dinv^2*v, then segmented pool by sorted batch id
__global__ void conv_final_k(const unsigned int* __restrict__ binned,
                             const int* __restrict__ cursor,
                             const float* __restrict__ wb, const float* __restrict__ dinv,
                             const float* __restrict__ v, const float* __restrict__ sc,
                             const int* __restrict__ batch, float* __restrict__ out, int n) {
    __shared__ float acc[RNODES];
    __shared__ float tbuf[RNODES];
    __shared__ int gbuf[RNODES];
    int tid = threadIdx.x, b = blockIdx.x;
    if (tid < RNODES) acc[tid] = 0.f;
    __syncthreads();
    int s0 = b * BCAP;
    int cnt = cursor[b];
    if (cnt > BCAP) cnt = BCAP;
    int nvec = cnt >> 2;
    for (int k = tid; k < nvec; k += blockDim.x) {
        uint4 p = *reinterpret_cast<const uint4*>(binned + s0 + 4 * k);
        float wx = wb[p.x & 0x1FFFF];
        float wy = wb[p.y & 0x1FFFF];
        float wz = wb[p.z & 0x1FFFF];
        float ww = wb[p.w & 0x1FFFF];
        atomicAdd(&acc[p.x >> 17], wx);
        atomicAdd(&acc[p.y >> 17], wy);
        atomicAdd(&acc[p.z >> 17], wz);
        atomicAdd(&acc[p.w >> 17], ww);
    }
    int i = 4 * nvec + tid;
    if (i < cnt) { unsigned p = binned[s0 + i]; atomicAdd(&acc[p >> 17], wb[p & 0x1FFFF]); }
    __syncthreads();
    int g = (b << RSHIFT) + tid;
    float tval = 0.f; int gid = -1;
    if (tid < RNODES && g < n) {
        float di = dinv[g];
        tval = sc[1] + di * acc[tid] + di * di * v[g];
        gid = batch[g];
    }
    if (tid < RNODES) { tbuf[tid] = tval; gbuf[tid] = gid; }
    __syncthreads();
    if (tid < RNODES && g < n) {
        bool head = (tid == 0) || (gbuf[tid - 1] != gid);
        if (head) {
            float s = 0.f;
            int i2 = tid;
            while (i2 < RNODES && gbuf[i2] == gid) { s += tbuf[i2]; ++i2; }
            atomicAdd(&out[gid], s);
        }
    }
}

extern "C" void kernel_launch(void* const* d_in, const int* in_sizes, int n_in,
                              void* d_out, int out_size, void* d_ws, size_t ws_size,
                              hipStream_t stream)
{
    const float* x    = (const float*)d_in[0];
    const int*   ei   = (const int*)d_in[1];
    const int*   batch= (const int*)d_in[2];
    const float* W1   = (const float*)d_in[3];
    const float* b1   = (const float*)d_in[4];
    const float* W2   = (const float*)d_in[5];
    const float* b2   = (const float*)d_in[6];
    const float* Wf1  = (const float*)d_in[7];
    const float* bf1  = (const float*)d_in[8];
    const float* Wf2  = (const float*)d_in[9];
    const float* bf2  = (const float*)d_in[10];
    const float* Wf3  = (const float*)d_in[11];
    const float* bf3  = (const float*)d_in[12];
    const float* Wo   = (const float*)d_in[13];
    const float* bo   = (const float*)d_in[14];
    float* out = (float*)d_out;

    const int n = in_sizes[0] / 64;
    const int E = in_sizes[1] / 2;
    const int G = out_size;
    const int* src = ei;
    const int* dst = ei + E;
    const int nb = (n + RNODES - 1) >> RSHIFT;

    // workspace layout (element offsets, all blocks 16B-aligned)
    float* ws_f = (float*)d_ws;
    int*   ws_i = (int*)d_ws;
    float* w1c    = ws_f;                    // 64
    float* sc     = ws_f + 64;               // 3 (+pad to 128)
    int*   cursor = ws_i + 128;              // NB_MAX
    size_t off_u  = 128 + (size_t)NB_MAX;
    float* u      = ws_f + off_u;            // n
    float* dinv   = u + n;                   // n
    float* w      = dinv + n;                // n
    float* v      = w + n;                   // n
    float* wb     = v + n;                   // n
    size_t off_b  = off_u + 5*(size_t)n;
    off_b = (off_b + 3) & ~(size_t)3;
    unsigned int* binned = (unsigned int*)(ws_f + off_b);   // nb * BCAP

    int chunk = (E + GRID - 1) / GRID;
    chunk = (chunk + 3) & ~3;
    int npb = (n + GRID - 1) / GRID;

    hipLaunchKernelGGL(collapse_weights_k, dim3(1), dim3(64), 0, stream,
                       W1, b1, W2, b2, Wf1, bf1, Wf2, bf2, Wf3, bf3, Wo, bo,
                       w1c, sc, cursor, out, G);
    hipLaunchKernelGGL(scatter_u_k, dim3(GRID), dim3(THREADS), 0, stream,
                       x, w1c, u, src, dst, E, n, npb, chunk, nb, cursor, binned);
    hipLaunchKernelGGL(degree_dinv_k, dim3(nb), dim3(512), 0, stream,
                       binned, cursor, u, dinv, w, n);
    hipLaunchKernelGGL(conv_mid_k, dim3(nb), dim3(512), 0, stream,
                       binned, cursor, w, dinv, u, sc, v, wb, n);
    hipLaunchKernelGGL(conv_final_k, dim3(nb), dim3(512), 0, stream,
                       binned, cursor, wb, dinv, v, sc, batch, out, n);
}